// Round 2
// baseline (94.176 us; speedup 1.0000x reference)
//
#include <hip/hip_runtime.h>
#include <hip/hip_bf16.h>

#define NCLS 1000
#define NDF  256
#define BB   512
#define MAXOCC 64
#define OSTRIDE 1024   // padded j-stride for fcT and O rows
#define NCOLS 1024     // 512 G cols (fc.df_i) + 512 H cols (fc.a_s)
#define ITILE 8

// Kernel 1: occurrence structure. occOf[i] = 1-based occurrence index of gt[i]
// within gt[0..i]; occStep[t*MAXOCC + m-1] = step index of m-th occurrence of t.
__global__ void occ_kernel(const int* __restrict__ gt, int* __restrict__ occOf,
                           int* __restrict__ occStep) {
    __shared__ int s_gt[BB];
    int tid = threadIdx.x;
    s_gt[tid] = gt[tid];
    __syncthreads();
    int t = s_gt[tid];
    int n = 0;
    for (int k = 0; k <= tid; ++k) n += (s_gt[k] == t) ? 1 : 0;
    occOf[tid] = n;
    if (n <= MAXOCC) occStep[t * MAXOCC + (n - 1)] = tid;
}

// Kernel 2: a-vectors. A[i] = df[i] - mean(df over occurrences 1..n_i of class gt[i]).
__global__ void amat_kernel(const float* __restrict__ df, const int* __restrict__ gt,
                            const int* __restrict__ occOf, const int* __restrict__ occStep,
                            float* __restrict__ A) {
    int i = blockIdx.x, d = threadIdx.x;
    int t = gt[i];
    int n = occOf[i];
    float sum = 0.f;
    for (int m = 0; m < n; ++m) {
        int s = occStep[t * MAXOCC + m];
        sum += df[s * NDF + d];
    }
    A[i * NDF + d] = df[i * NDF + d] - sum / (float)n;
}

// Kernel 3: fcT[d][j] = fc[j][d], row stride OSTRIDE (pad cols >= NCLS left as-is).
__global__ void transpose_fc(const float* __restrict__ fc, float* __restrict__ fcT) {
    __shared__ float tile[32][33];
    int jb = blockIdx.x * 32, db = blockIdx.y * 32;
    int tid = threadIdx.x;
    int c = tid & 31, r = tid >> 5;  // 256 threads: 8 rows per pass
    for (int rr = r; rr < 32; rr += 8) {
        int j = jb + rr;
        if (j < NCLS) tile[rr][c] = fc[j * NDF + db + c];
    }
    __syncthreads();
    for (int rr = r; rr < 32; rr += 8) {
        int j = jb + c;
        if (j < NCLS) fcT[(db + rr) * OSTRIDE + j] = tile[c][rr];
    }
}

// Kernel 4: O[col][j] = sum_d Bmat[col][d] * fc[j][d], Bmat = [df ; A] (1024 x 256).
// grid (2, NCOLS/ITILE), 256 threads; each thread owns 2 consecutive j.
__global__ void gemm_kernel(const float* __restrict__ df, const float* __restrict__ A,
                            const float* __restrict__ fcT, float* __restrict__ O) {
    __shared__ float Bs[ITILE][64];
    int tid = threadIdx.x;
    int j0 = blockIdx.x * 512 + tid * 2;
    int c0 = blockIdx.y * ITILE;
    float acc[ITILE][2];
#pragma unroll
    for (int ii = 0; ii < ITILE; ++ii) { acc[ii][0] = 0.f; acc[ii][1] = 0.f; }
    for (int d0 = 0; d0 < NDF; d0 += 64) {
        for (int e = tid; e < ITILE * 64; e += 256) {
            int ii = e >> 6, dd = e & 63;
            int col = c0 + ii;
            const float* src = (col < BB) ? (df + col * NDF) : (A + (col - BB) * NDF);
            Bs[ii][dd] = src[d0 + dd];
        }
        __syncthreads();
#pragma unroll 8
        for (int dd = 0; dd < 64; ++dd) {
            float2 fv = *reinterpret_cast<const float2*>(&fcT[(d0 + dd) * OSTRIDE + j0]);
#pragma unroll
            for (int ii = 0; ii < ITILE; ++ii) {
                acc[ii][0] += Bs[ii][dd] * fv.x;
                acc[ii][1] += Bs[ii][dd] * fv.y;
            }
        }
        __syncthreads();
    }
#pragma unroll
    for (int ii = 0; ii < ITILE; ++ii) {
        *reinterpret_cast<float2*>(&O[(size_t)(c0 + ii) * OSTRIDE + j0]) =
            make_float2(acc[ii][0], acc[ii][1]);
    }
}

// Kernel 5: scores[i][j] = (G[i][j]-G[i][t]) + 0.05 * sum_{m=2..n} ((m-1)/(m n)) (H[s_m][j]-H[s_m][t])^2
// Output is float32 (reference returns fp32).
__global__ void combine_kernel(const int* __restrict__ gt, const int* __restrict__ occOf,
                               const int* __restrict__ occStep, const float* __restrict__ O,
                               float* __restrict__ out) {
    int i = blockIdx.y;
    int j = blockIdx.x * 256 + threadIdx.x;
    if (j >= NCLS) return;
    int t = gt[i];
    int n = occOf[i];
    const float* Grow = O + (size_t)i * OSTRIDE;
    float g = Grow[j] - Grow[t];
    float q = 0.f;
    for (int m = 2; m <= n; ++m) {
        int s = occStep[t * MAXOCC + (m - 1)];
        const float* Hrow = O + (size_t)(BB + s) * OSTRIDE;
        float h = Hrow[j] - Hrow[t];
        q += ((float)(m - 1) / ((float)m * (float)n)) * h * h;
    }
    out[(size_t)i * NCLS + j] = g + 0.05f * q;  // 0.5*ALP = 0.05
}

extern "C" void kernel_launch(void* const* d_in, const int* in_sizes, int n_in,
                              void* d_out, int out_size, void* d_ws, size_t ws_size,
                              hipStream_t stream) {
    const float* df = (const float*)d_in[0];
    const int*   gt = (const int*)d_in[1];
    const float* fc = (const float*)d_in[2];
    float* out = (float*)d_out;

    char* ws = (char*)d_ws;
    int*   occOf   = (int*)ws;                                   // 2048 B (pad to 4096)
    int*   occStep = (int*)(ws + 4096);                          // 1000*64*4 = 256000 (pad 262144)
    float* A       = (float*)(ws + 4096 + 262144);               // 512*256*4 = 524288
    float* fcT     = (float*)(ws + 4096 + 262144 + 524288);      // 256*1024*4 = 1048576
    float* O       = (float*)(ws + 4096 + 262144 + 524288 + 1048576); // 1024*1024*4 = 4 MB
    // total ~5.8 MB of ws

    occ_kernel<<<1, BB, 0, stream>>>(gt, occOf, occStep);
    amat_kernel<<<BB, NDF, 0, stream>>>(df, gt, occOf, occStep, A);
    transpose_fc<<<dim3(32, 8), 256, 0, stream>>>(fc, fcT);
    gemm_kernel<<<dim3(2, NCOLS / ITILE), 256, 0, stream>>>(df, A, fcT, O);
    combine_kernel<<<dim3(4, BB), 256, 0, stream>>>(gt, occOf, occStep, O, out);
}

// Round 3
// 28.180 us; speedup vs baseline: 3.3419x; 3.3419x over previous
//
#include <hip/hip_runtime.h>

#define NCLS 1000
#define NDF  256
#define BB   512
#define MAXOCC 64
#define DFT_LD 512    // dfT row stride (K-major df)
#define FCT_LD 1024   // fcT row stride (K-major fc, zero-padded cols 1000..1023)
#define O_LD   1024   // G row stride

// K1: occurrence structure. occOf[i] = 1-based occurrence index of gt[i] within
// gt[0..i]; occStep[t*MAXOCC + m-1] = step index of the m-th occurrence of t.
__global__ void occ_kernel(const int* __restrict__ gt, int* __restrict__ occOf,
                           int* __restrict__ occStep) {
    __shared__ int s_gt[BB];
    int tid = threadIdx.x;
    s_gt[tid] = gt[tid];
    __syncthreads();
    int t = s_gt[tid];
    int n = 0;
    for (int k = 0; k <= tid; ++k) n += (s_gt[k] == t) ? 1 : 0;
    occOf[tid] = n;
    if (n <= MAXOCC) occStep[t * MAXOCC + (n - 1)] = tid;
}

// K2: K-major transposes. blockIdx.x<16 -> df tile, else fc tile (zero pad j>=1000).
__global__ void transpose_kernel(const float* __restrict__ df, const float* __restrict__ fc,
                                 float* __restrict__ dfT, float* __restrict__ fcT) {
    __shared__ float tile[32][33];
    int bx = blockIdx.x, kb = blockIdx.y * 32;
    int tid = threadIdx.x;
    int c = tid & 31, r0 = tid >> 5;
    if (bx < 16) {
        int rb = bx * 32;
        for (int rr = r0; rr < 32; rr += 8)
            tile[rr][c] = df[(rb + rr) * NDF + kb + c];
        __syncthreads();
        for (int rr = r0; rr < 32; rr += 8)
            dfT[(kb + rr) * DFT_LD + rb + c] = tile[c][rr];
    } else {
        int rb = (bx - 16) * 32;
        for (int rr = r0; rr < 32; rr += 8) {
            int j = rb + rr;
            tile[rr][c] = (j < NCLS) ? fc[j * NDF + kb + c] : 0.f;
        }
        __syncthreads();
        for (int rr = r0; rr < 32; rr += 8)
            fcT[(kb + rr) * FCT_LD + rb + c] = tile[c][rr];
    }
}

// K3: G[m][j] = sum_k df[m][k] * fc[j][k], from K-major dfT/fcT.
// BM=32, BN=64, BK=32; 256 threads; per-thread 4x2; LDS double-buffer with
// register prefetch; one barrier per K-chunk.
#define BM 32
#define BN 64
#define BK 32
__global__ __launch_bounds__(256) void gemm_kernel(const float* __restrict__ dfT,
                                                   const float* __restrict__ fcT,
                                                   float* __restrict__ O) {
    __shared__ float As[2][BK][BM];
    __shared__ float Bs[2][BK][BN];
    int tid = threadIdx.x;
    int tx = tid & 31;          // j groups of 2
    int ty = tid >> 5;          // m groups of 4
    int m0 = blockIdx.y * BM, j0 = blockIdx.x * BN;
    int a_kk = tid >> 3, a_m = (tid & 7) * 4;
    int b_kk = tid >> 4, b_j = (tid & 15) * 4;

    float4 va  = *(const float4*)&dfT[a_kk * DFT_LD + m0 + a_m];
    float4 vb0 = *(const float4*)&fcT[b_kk * FCT_LD + j0 + b_j];
    float4 vb1 = *(const float4*)&fcT[(b_kk + 16) * FCT_LD + j0 + b_j];
    *(float4*)&As[0][a_kk][a_m] = va;
    *(float4*)&Bs[0][b_kk][b_j] = vb0;
    *(float4*)&Bs[0][b_kk + 16][b_j] = vb1;
    __syncthreads();

    float acc[4][2] = {};
    const int NCHUNK = NDF / BK;
    for (int c = 0; c < NCHUNK; ++c) {
        int cur = c & 1, nxt = cur ^ 1;
        if (c + 1 < NCHUNK) {
            int k0 = (c + 1) * BK;
            va  = *(const float4*)&dfT[(k0 + a_kk) * DFT_LD + m0 + a_m];
            vb0 = *(const float4*)&fcT[(k0 + b_kk) * FCT_LD + j0 + b_j];
            vb1 = *(const float4*)&fcT[(k0 + 16 + b_kk) * FCT_LD + j0 + b_j];
        }
#pragma unroll
        for (int kk = 0; kk < BK; ++kk) {
            float4 a = *(const float4*)&As[cur][kk][ty * 4];
            float2 b = *(const float2*)&Bs[cur][kk][tx * 2];
            acc[0][0] += a.x * b.x; acc[0][1] += a.x * b.y;
            acc[1][0] += a.y * b.x; acc[1][1] += a.y * b.y;
            acc[2][0] += a.z * b.x; acc[2][1] += a.z * b.y;
            acc[3][0] += a.w * b.x; acc[3][1] += a.w * b.y;
        }
        if (c + 1 < NCHUNK) {
            *(float4*)&As[nxt][a_kk][a_m] = va;
            *(float4*)&Bs[nxt][b_kk][b_j] = vb0;
            *(float4*)&Bs[nxt][b_kk + 16][b_j] = vb1;
            __syncthreads();
        }
    }
#pragma unroll
    for (int r = 0; r < 4; ++r) {
        *(float2*)&O[(size_t)(m0 + ty * 4 + r) * O_LD + j0 + tx * 2] =
            make_float2(acc[r][0], acc[r][1]);
    }
}

// K4: scores[i][j] = G[i][j]-G[i][t]
//   + 0.05 * sum_{m=2..n} ((m-1)/(m*n)) * (h_m[j]-h_m[t])^2
// with h_m[j] = G[s_m][j] - (1/m) * sum_{m'<=m} G[s_m'][j]   (A = df - prefix-mean)
__global__ void combine_kernel(const int* __restrict__ gt, const int* __restrict__ occOf,
                               const int* __restrict__ occStep, const float* __restrict__ O,
                               float* __restrict__ out) {
    int i = blockIdx.y;
    int j = blockIdx.x * 256 + threadIdx.x;
    if (j >= NCLS) return;
    int t = gt[i];
    int n = occOf[i];
    const float* Grow = O + (size_t)i * O_LD;
    float g = Grow[j] - Grow[t];
    float q = 0.f;
    if (n >= 2) {
        float S = 0.f, St = 0.f;
        for (int m = 1; m <= n; ++m) {
            int s = occStep[t * MAXOCC + (m - 1)];
            float Gsj = O[(size_t)s * O_LD + j];
            float Gst = O[(size_t)s * O_LD + t];
            S += Gsj; St += Gst;
            if (m >= 2) {
                float inv_m = 1.f / (float)m;
                float h = (Gsj - S * inv_m) - (Gst - St * inv_m);
                q += ((float)(m - 1) * inv_m / (float)n) * h * h;
            }
        }
    }
    out[(size_t)i * NCLS + j] = g + 0.05f * q;  // 0.5*ALP = 0.05
}

extern "C" void kernel_launch(void* const* d_in, const int* in_sizes, int n_in,
                              void* d_out, int out_size, void* d_ws, size_t ws_size,
                              hipStream_t stream) {
    const float* df = (const float*)d_in[0];
    const int*   gt = (const int*)d_in[1];
    const float* fc = (const float*)d_in[2];
    float* out = (float*)d_out;

    char* ws = (char*)d_ws;
    int*   occOf   = (int*)ws;                                    // 4096 B slot
    int*   occStep = (int*)(ws + 4096);                           // 256000 B (slot 262144)
    float* dfT     = (float*)(ws + 4096 + 262144);                // 256*512*4  = 524288
    float* fcT     = (float*)(ws + 4096 + 262144 + 524288);       // 256*1024*4 = 1048576
    float* O       = (float*)(ws + 4096 + 262144 + 524288 + 1048576); // 512*1024*4 = 2 MB
    // total ~3.8 MB of ws

    occ_kernel<<<1, BB, 0, stream>>>(gt, occOf, occStep);
    transpose_kernel<<<dim3(48, 8), 256, 0, stream>>>(df, fc, dfT, fcT);
    gemm_kernel<<<dim3(16, 16), 256, 0, stream>>>(dfT, fcT, O);
    combine_kernel<<<dim3(4, BB), 256, 0, stream>>>(gt, occOf, occStep, O, out);
}